// Round 5
// baseline (939.792 us; speedup 1.0000x reference)
//
#include <hip/hip_runtime.h>

namespace {
constexpr int kB = 32;       // batch
constexpr int kN = 32768;    // num_primary
constexpr int kQ = 8;        // dim_primary
constexpr int kD = 10;       // num_digit
constexpr int kV = 16;       // dim_digit
constexpr int kRows = kB * kD;        // 320
constexpr int kNT = 4;                // n per tile
constexpr int kTiles = kN / kNT;      // 8192
constexpr int kThreads = 512;         // 8 waves; wave = bgrp; lane = dslot*4+vq
constexpr int kGrid = 512;            // 2 blocks/CU; 16 tiles/block
// LDS W layout: per (n_l,d) a 576B block (36 chunks: 32 real [qh][v] + 4 pad).
// chunk(qh,v) at offset qh*256 + v*16. d-stride 576 => per-instr addresses
// (10 dd x 4 vq) spread 5-deep balanced over the 8 bank-quads.
constexpr int kWBlk = 576;
constexpr int kWReg = 23552;               // 1472 chunks = 23 wave-strips
constexpr int kUReg = kNT * kB * 32;       // 4096 B = 4 strips
constexpr int kBuf = kWReg + kUReg;        // 27648 B
}

__device__ __forceinline__ void g2lds16(const void* g, void* l) {
  __builtin_amdgcn_global_load_lds(
      (const __attribute__((address_space(1))) unsigned int*)g,
      (__attribute__((address_space(3))) unsigned int*)l, 16, 0, 0);
}

template <int CTRL>
__device__ __forceinline__ float dpp_mv(float x) {
  return __int_as_float(__builtin_amdgcn_update_dpp(
      0, __float_as_int(x), CTRL, 0xF, 0xF, true));
}

// Stage one tile (4 n): W region 23 strips of 1KB, u region 4 strips.
// LDS dst is wave-uniform strip base (HW adds lane*16); global src per-lane
// carries the [v][q] -> [qh][v-chunk] permutation (16B chunks contiguous both sides).
__device__ __forceinline__ void stage_tile(const float* __restrict__ u,
                                           const float* __restrict__ W,
                                           char* buf, int n0) {
  const int wv = threadIdx.x >> 6;
  const int ln = threadIdx.x & 63;
  #pragma unroll
  for (int k = 0; k < 4; ++k) {
    const int s = wv + 8 * k;  // wave-uniform strip id 0..31 (27 used)
    if (s < 23) {
      const int g = s * 64 + ln;        // chunk slot 0..1471
      const int blk = g / 36;           // (n_l, d) block
      const int c = g - blk * 36;       // chunk within block
      const char* src;
      if (g < 1440 && c < 32) {
        const int n_l = blk / 10, d = blk - n_l * 10;
        const int qh = c >> 4, v = c & 15;
        src = (const char*)W + ((size_t)d * kN + n0 + n_l) * 512 +
              (size_t)(v * 32 + qh * 16);
      } else {
        src = (const char*)W;  // filler into pad slots
      }
      g2lds16(src, buf + s * 1024);
    } else if (s < 27) {
      const int s2 = s - 23;
      const int h = s2 * 64 + ln;       // 0..255
      const int n_l = h >> 6, r = h & 63, b = r >> 1, qh = r & 1;
      const char* src = (const char*)u +
          ((size_t)b * kN + n0 + n_l) * 32 + (size_t)qh * 16;
      g2lds16(src, buf + kWReg + s2 * 1024);
    }
  }
}

// PHASE 0: c = 1/10 exactly (folded into final scale). PHASE 1: softmax(u_hat.vprev).
template <int PHASE>
__launch_bounds__(kThreads, 3)
__global__ void routing_pass(const float* __restrict__ u,     // [B,N,Q]
                             const float* __restrict__ W,     // [D,N,V,Q]
                             const float* __restrict__ vprev, // [B,D,V]
                             float* __restrict__ s_out) {     // [B,D,V]
  __shared__ __align__(16) char smem[2 * kBuf];
  const int t = threadIdx.x;
  const int bgrp = t >> 6;       // wave id = b-group (4 b each)
  const int ln = t & 63;
  const int dslot = ln >> 2;     // 0..15, active if <10
  const int vq = ln & 3;         // v-quarter; thread's v = j*4+vq
  const bool act = (dslot < kD);
  const int dd = act ? dslot : dslot - kD;  // idle lanes alias real rows (broadcast)
  const int b0 = bgrp * 4;

  float vp[4][4];
  if constexpr (PHASE != 0) {
    #pragma unroll
    for (int bb = 0; bb < 4; ++bb)
      #pragma unroll
      for (int j = 0; j < 4; ++j)
        vp[bb][j] = vprev[((b0 + bb) * kD + dd) * kV + j * 4 + vq];
  }

  float acc[4][4];
  #pragma unroll
  for (int bb = 0; bb < 4; ++bb)
    #pragma unroll
    for (int j = 0; j < 4; ++j) acc[bb][j] = 0.0f;

  int tile = blockIdx.x;
  int cur = 0;
  stage_tile(u, W, smem, tile * kNT);

  for (; tile < kTiles; tile += kGrid) {
    __syncthreads();  // drains staged loads of cur; prev reads done
    const int nxt = tile + kGrid;
    if (nxt < kTiles)
      stage_tile(u, W, smem + (cur ^ 1) * kBuf, nxt * kNT);

    const char* base = smem + cur * kBuf;
    #pragma unroll
    for (int nl = 0; nl < kNT; ++nl) {
      // u[4b][8q] via wave-uniform broadcast reads
      float uu[4][8];
      const char* ub = base + kWReg + nl * 1024 + b0 * 32;
      #pragma unroll
      for (int bb = 0; bb < 4; ++bb) {
        const float4 a = *(const float4*)(ub + bb * 32);
        const float4 b4 = *(const float4*)(ub + bb * 32 + 16);
        uu[bb][0] = a.x; uu[bb][1] = a.y; uu[bb][2] = a.z; uu[bb][3] = a.w;
        uu[bb][4] = b4.x; uu[bb][5] = b4.y; uu[bb][6] = b4.z; uu[bb][7] = b4.w;
      }
      // u_hat partials: 4 b x 4 v per thread
      float uh[4][4];
      #pragma unroll
      for (int bb = 0; bb < 4; ++bb)
        #pragma unroll
        for (int j = 0; j < 4; ++j) uh[bb][j] = 0.0f;
      const char* wb = base + (nl * kD + dd) * kWBlk + vq * 16;
      #pragma unroll
      for (int qh = 0; qh < 2; ++qh) {
        #pragma unroll
        for (int j = 0; j < 4; ++j) {
          const float4 w4 = *(const float4*)(wb + qh * 256 + j * 64);
          #pragma unroll
          for (int bb = 0; bb < 4; ++bb) {
            uh[bb][j] = fmaf(w4.x, uu[bb][qh * 4 + 0], uh[bb][j]);
            uh[bb][j] = fmaf(w4.y, uu[bb][qh * 4 + 1], uh[bb][j]);
            uh[bb][j] = fmaf(w4.z, uu[bb][qh * 4 + 2], uh[bb][j]);
            uh[bb][j] = fmaf(w4.w, uu[bb][qh * 4 + 3], uh[bb][j]);
          }
        }
      }
      #pragma unroll
      for (int bb = 0; bb < 4; ++bb) {
        float c;
        if constexpr (PHASE != 0) {
          float lg = uh[bb][0] * vp[bb][0];
          lg = fmaf(uh[bb][1], vp[bb][1], lg);
          lg = fmaf(uh[bb][2], vp[bb][2], lg);
          lg = fmaf(uh[bb][3], vp[bb][3], lg);
          // vq all-reduce: quad_perm xor1 (0xB1), xor2 (0x4E) — VALU DPP
          lg += dpp_mv<0xB1>(lg);
          lg += dpp_mv<0x4E>(lg);
          const float e = act ? __expf(lg) : 0.0f;
          // softmax denom over 16 dslots: row_ror:4 (0x124), row_ror:8 (0x128)
          float den = e;
          den += dpp_mv<0x124>(den);
          den += dpp_mv<0x128>(den);
          den += __shfl_xor(den, 16);
          den += __shfl_xor(den, 32);
          c = e * __builtin_amdgcn_rcpf(den);
        } else {
          c = 1.0f;  // exact 1/10 folded into final scale
        }
        #pragma unroll
        for (int j = 0; j < 4; ++j) acc[bb][j] = fmaf(c, uh[bb][j], acc[bb][j]);
      }
    }
    cur ^= 1;
  }

  if (act) {
    const float scale = (PHASE == 0) ? 0.1f : 1.0f;
    #pragma unroll
    for (int bb = 0; bb < 4; ++bb) {
      float* srow = s_out + ((b0 + bb) * kD + dslot) * kV + vq;
      #pragma unroll
      for (int j = 0; j < 4; ++j)
        atomicAdd(&srow[j * 4], acc[bb][j] * scale);
    }
  }
}

// squash per (b,d) row. MODE 0: vprev = squash(s); s = 0
//                       MODE 1: vprev += squash(s); s = 0
//                       MODE 2: out = squash(s)
template <int MODE>
__global__ void squash_kernel(float* __restrict__ s,
                              float* __restrict__ vprev,
                              float* __restrict__ out) {
  const int t = threadIdx.x;
  if (t >= kRows) return;
  float* sr = s + t * kV;
  float sv[kV];
  float n2 = 0.0f;
  #pragma unroll
  for (int v = 0; v < kV; ++v) {
    sv[v] = sr[v];
    n2 = fmaf(sv[v], sv[v], n2);
  }
  if (MODE != 2) {
    #pragma unroll
    for (int v = 0; v < kV; ++v) sr[v] = 0.0f;  // ready for next pass
  }
  const float norm = sqrtf(n2);
  const float coef = n2 / ((n2 + 1.0f) * (norm + 1e-7f));
  float* dst = (MODE == 2) ? (out + t * kV) : (vprev + t * kV);
  #pragma unroll
  for (int v = 0; v < kV; ++v) {
    float val = coef * sv[v];
    if (MODE == 1) val += dst[v];
    dst[v] = val;
  }
}

extern "C" void kernel_launch(void* const* d_in, const int* in_sizes, int n_in,
                              void* d_out, int out_size, void* d_ws, size_t ws_size,
                              hipStream_t stream) {
  const float* u = reinterpret_cast<const float*>(d_in[0]);  // primary_caps [B,N,Q]
  const float* W = reinterpret_cast<const float*>(d_in[1]);  // W [D,N,V,Q]
  float* out = reinterpret_cast<float*>(d_out);              // v [B,D,V] fp32

  float* s = reinterpret_cast<float*>(d_ws);   // [B,D,V] accumulator
  float* vprev = s + kRows * kV;               // [B,D,V] running v / vsum
  const size_t sbytes = (size_t)kRows * kV * sizeof(float);

  // r = 0: c uniform -> s0 = 0.1 * sum_n u_hat ; v0 = squash(s0)
  (void)hipMemsetAsync(s, 0, sbytes, stream);
  routing_pass<0><<<kGrid, kThreads, 0, stream>>>(u, W, nullptr, s);
  squash_kernel<0><<<1, kThreads, 0, stream>>>(s, vprev, out);

  // r = 1: logits = u_hat . v0 ; v1 = squash(s1) ; vprev = v0 + v1
  routing_pass<1><<<kGrid, kThreads, 0, stream>>>(u, W, vprev, s);
  squash_kernel<1><<<1, kThreads, 0, stream>>>(s, vprev, out);

  // r = 2: logits = u_hat . (v0+v1) ; out = squash(s2)
  routing_pass<1><<<kGrid, kThreads, 0, stream>>>(u, W, vprev, s);
  squash_kernel<2><<<1, kThreads, 0, stream>>>(s, vprev, out);
}

// Round 6
// 569.468 us; speedup vs baseline: 1.6503x; 1.6503x over previous
//
#include <hip/hip_runtime.h>

namespace {
constexpr int kB = 32;       // batch
constexpr int kN = 32768;    // num_primary
constexpr int kQ = 8;        // dim_primary
constexpr int kD = 10;       // num_digit
constexpr int kV = 16;       // dim_digit
constexpr int kRows = kB * kD;        // 320
constexpr int kNT = 4;                // n per tile
constexpr int kTiles = kN / kNT;      // 8192
constexpr int kThreads = 512;         // 8 waves; wave = bgrp; lane = dslot*4+vq
constexpr int kGrid = 512;            // 2 blocks/CU; 16 tiles/block
// LDS W layout: per (n_l,d) a 576B block (36 chunks: 32 real [qh][v] + 4 pad).
// chunk(qh,v) at offset qh*256 + v*16. d-stride 576 => per-instr addresses
// (10 dd x 4 vq) spread 5-deep balanced over the 8 bank-quads.
constexpr int kWBlk = 576;
constexpr int kWReg = 23552;               // 1472 chunks = 23 wave-strips
constexpr int kUReg = kNT * kB * 32;       // 4096 B = 4 strips
constexpr int kBuf = kWReg + kUReg;        // 27648 B
}

__device__ __forceinline__ void g2lds16(const void* g, void* l) {
  __builtin_amdgcn_global_load_lds(
      (const __attribute__((address_space(1))) unsigned int*)g,
      (__attribute__((address_space(3))) unsigned int*)l, 16, 0, 0);
}

template <int CTRL>
__device__ __forceinline__ float dpp_mv(float x) {
  return __int_as_float(__builtin_amdgcn_update_dpp(
      0, __float_as_int(x), CTRL, 0xF, 0xF, true));
}

// Stage one tile (4 n): W region 23 strips of 1KB, u region 4 strips.
// LDS dst is wave-uniform strip base (HW adds lane*16); global src per-lane
// carries the [v][q] -> [qh][v-chunk] permutation (16B chunks contiguous both sides).
__device__ __forceinline__ void stage_tile(const float* __restrict__ u,
                                           const float* __restrict__ W,
                                           char* buf, int n0) {
  const int wv = threadIdx.x >> 6;
  const int ln = threadIdx.x & 63;
  #pragma unroll
  for (int k = 0; k < 4; ++k) {
    const int s = wv + 8 * k;  // wave-uniform strip id 0..31 (27 used)
    if (s < 23) {
      const int g = s * 64 + ln;        // chunk slot 0..1471
      const int blk = g / 36;           // (n_l, d) block
      const int c = g - blk * 36;       // chunk within block
      const char* src;
      if (g < 1440 && c < 32) {
        const int n_l = blk / 10, d = blk - n_l * 10;
        const int qh = c >> 4, v = c & 15;
        src = (const char*)W + ((size_t)d * kN + n0 + n_l) * 512 +
              (size_t)(v * 32 + qh * 16);
      } else {
        src = (const char*)W;  // filler into pad slots
      }
      g2lds16(src, buf + s * 1024);
    } else if (s < 27) {
      const int s2 = s - 23;
      const int h = s2 * 64 + ln;       // 0..255
      const int n_l = h >> 6, r = h & 63, b = r >> 1, qh = r & 1;
      const char* src = (const char*)u +
          ((size_t)b * kN + n0 + n_l) * 32 + (size_t)qh * 16;
      g2lds16(src, buf + kWReg + s2 * 1024);
    }
  }
}

// PHASE 0: c = 1/10 exactly (folded into final scale). PHASE 1: softmax(u_hat.vprev).
template <int PHASE>
__launch_bounds__(kThreads, 2)   // 2 blocks/CU -> 128-VGPR budget; LDS caps at 2 anyway
__global__ void routing_pass(const float* __restrict__ u,     // [B,N,Q]
                             const float* __restrict__ W,     // [D,N,V,Q]
                             const float* __restrict__ vprev, // [B,D,V]
                             float* __restrict__ s_out) {     // [B,D,V]
  __shared__ __align__(16) char smem[2 * kBuf];
  const int t = threadIdx.x;
  const int bgrp = t >> 6;       // wave id = b-group (4 b each)
  const int ln = t & 63;
  const int dslot = ln >> 2;     // 0..15, active if <10
  const int vq = ln & 3;         // v-quarter; thread's v = j*4+vq
  const bool act = (dslot < kD);
  const int dd = act ? dslot : dslot - kD;  // idle lanes alias real rows (broadcast)
  const int b0 = bgrp * 4;

  float vp[4][4];
  if constexpr (PHASE != 0) {
    #pragma unroll
    for (int bb = 0; bb < 4; ++bb)
      #pragma unroll
      for (int j = 0; j < 4; ++j)
        vp[bb][j] = vprev[((b0 + bb) * kD + dd) * kV + j * 4 + vq];
  }

  float acc[4][4];
  #pragma unroll
  for (int bb = 0; bb < 4; ++bb)
    #pragma unroll
    for (int j = 0; j < 4; ++j) acc[bb][j] = 0.0f;

  int tile = blockIdx.x;
  int cur = 0;
  stage_tile(u, W, smem, tile * kNT);

  for (; tile < kTiles; tile += kGrid) {
    __syncthreads();  // drains staged loads of cur; prev reads done
    const int nxt = tile + kGrid;
    if (nxt < kTiles)
      stage_tile(u, W, smem + (cur ^ 1) * kBuf, nxt * kNT);

    const char* base = smem + cur * kBuf;
    #pragma unroll
    for (int nl = 0; nl < kNT; ++nl) {
      float uh[4][4];
      #pragma unroll
      for (int bb = 0; bb < 4; ++bb)
        #pragma unroll
        for (int j = 0; j < 4; ++j) uh[bb][j] = 0.0f;
      const char* wb = base + (nl * kD + dd) * kWBlk + vq * 16;
      const char* ub = base + kWReg + nl * 1024 + b0 * 32;
      #pragma unroll
      for (int qh = 0; qh < 2; ++qh) {
        // u[4b][4q] for this q-half: wave-uniform broadcast reads (16 floats live)
        float uu[4][4];
        #pragma unroll
        for (int bb = 0; bb < 4; ++bb) {
          const float4 a = *(const float4*)(ub + bb * 32 + qh * 16);
          uu[bb][0] = a.x; uu[bb][1] = a.y; uu[bb][2] = a.z; uu[bb][3] = a.w;
        }
        #pragma unroll
        for (int j = 0; j < 4; ++j) {
          const float4 w4 = *(const float4*)(wb + qh * 256 + j * 64);
          #pragma unroll
          for (int bb = 0; bb < 4; ++bb) {
            uh[bb][j] = fmaf(w4.x, uu[bb][0], uh[bb][j]);
            uh[bb][j] = fmaf(w4.y, uu[bb][1], uh[bb][j]);
            uh[bb][j] = fmaf(w4.z, uu[bb][2], uh[bb][j]);
            uh[bb][j] = fmaf(w4.w, uu[bb][3], uh[bb][j]);
          }
        }
      }
      #pragma unroll
      for (int bb = 0; bb < 4; ++bb) {
        float c;
        if constexpr (PHASE != 0) {
          float lg = uh[bb][0] * vp[bb][0];
          lg = fmaf(uh[bb][1], vp[bb][1], lg);
          lg = fmaf(uh[bb][2], vp[bb][2], lg);
          lg = fmaf(uh[bb][3], vp[bb][3], lg);
          // vq all-reduce: quad_perm xor1 (0xB1), xor2 (0x4E) — VALU DPP
          lg += dpp_mv<0xB1>(lg);
          lg += dpp_mv<0x4E>(lg);
          const float e = act ? __expf(lg) : 0.0f;
          // softmax denom over 16 dslots: row_ror:4 (0x124), row_ror:8 (0x128)
          float den = e;
          den += dpp_mv<0x124>(den);
          den += dpp_mv<0x128>(den);
          den += __shfl_xor(den, 16);
          den += __shfl_xor(den, 32);
          c = e * __builtin_amdgcn_rcpf(den);
        } else {
          c = 1.0f;  // exact 1/10 folded into final scale
        }
        #pragma unroll
        for (int j = 0; j < 4; ++j) acc[bb][j] = fmaf(c, uh[bb][j], acc[bb][j]);
      }
    }
    cur ^= 1;
  }

  if (act) {
    const float scale = (PHASE == 0) ? 0.1f : 1.0f;
    #pragma unroll
    for (int bb = 0; bb < 4; ++bb) {
      float* srow = s_out + ((b0 + bb) * kD + dslot) * kV + vq;
      #pragma unroll
      for (int j = 0; j < 4; ++j)
        atomicAdd(&srow[j * 4], acc[bb][j] * scale);
    }
  }
}

// squash per (b,d) row. MODE 0: vprev = squash(s); s = 0
//                       MODE 1: vprev += squash(s); s = 0
//                       MODE 2: out = squash(s)
template <int MODE>
__global__ void squash_kernel(float* __restrict__ s,
                              float* __restrict__ vprev,
                              float* __restrict__ out) {
  const int t = threadIdx.x;
  if (t >= kRows) return;
  float* sr = s + t * kV;
  float sv[kV];
  float n2 = 0.0f;
  #pragma unroll
  for (int v = 0; v < kV; ++v) {
    sv[v] = sr[v];
    n2 = fmaf(sv[v], sv[v], n2);
  }
  if (MODE != 2) {
    #pragma unroll
    for (int v = 0; v < kV; ++v) sr[v] = 0.0f;  // ready for next pass
  }
  const float norm = sqrtf(n2);
  const float coef = n2 / ((n2 + 1.0f) * (norm + 1e-7f));
  float* dst = (MODE == 2) ? (out + t * kV) : (vprev + t * kV);
  #pragma unroll
  for (int v = 0; v < kV; ++v) {
    float val = coef * sv[v];
    if (MODE == 1) val += dst[v];
    dst[v] = val;
  }
}

extern "C" void kernel_launch(void* const* d_in, const int* in_sizes, int n_in,
                              void* d_out, int out_size, void* d_ws, size_t ws_size,
                              hipStream_t stream) {
  const float* u = reinterpret_cast<const float*>(d_in[0]);  // primary_caps [B,N,Q]
  const float* W = reinterpret_cast<const float*>(d_in[1]);  // W [D,N,V,Q]
  float* out = reinterpret_cast<float*>(d_out);              // v [B,D,V] fp32

  float* s = reinterpret_cast<float*>(d_ws);   // [B,D,V] accumulator
  float* vprev = s + kRows * kV;               // [B,D,V] running v / vsum
  const size_t sbytes = (size_t)kRows * kV * sizeof(float);

  // r = 0: c uniform -> s0 = 0.1 * sum_n u_hat ; v0 = squash(s0)
  (void)hipMemsetAsync(s, 0, sbytes, stream);
  routing_pass<0><<<kGrid, kThreads, 0, stream>>>(u, W, nullptr, s);
  squash_kernel<0><<<1, kThreads, 0, stream>>>(s, vprev, out);

  // r = 1: logits = u_hat . v0 ; v1 = squash(s1) ; vprev = v0 + v1
  routing_pass<1><<<kGrid, kThreads, 0, stream>>>(u, W, vprev, s);
  squash_kernel<1><<<1, kThreads, 0, stream>>>(s, vprev, out);

  // r = 2: logits = u_hat . (v0+v1) ; out = squash(s2)
  routing_pass<1><<<kGrid, kThreads, 0, stream>>>(u, W, vprev, s);
  squash_kernel<2><<<1, kThreads, 0, stream>>>(s, vprev, out);
}